// Round 1
// baseline (4550.724 us; speedup 1.0000x reference)
//
#include <hip/hip_runtime.h>
#include <hip/hip_bf16.h>
#include <float.h>

// OneHopRanker on MI355X.
// Inputs: d_in[0]=contexts [256x128] f32, d_in[1]=enc_ans [500000x128] f32,
//         d_in[2]=enc_ctx [500000x128] f32, d_in[3]=k (=32, hardcoded).
// Output: d_out = int32 [256x32] answer indices (top-k, descending score).
//
// Strategy: hierarchical exact top-k. Stage 1 computes per-(query, 64-cand
// tile) max score (fused fp32 GEMM + wave max-reduce). Stage 2 per query
// picks top-32 tiles by max, rescans their 2048 candidates exactly, and
// extracts the top-32 (value desc, index asc).

#define TILE 64
#define KSEL 32
#define QB 8
#define NT_MAX 7936   // >= ceil(500000/64)=7813
#define LDS_STRIDE 132  // floats; 528 B = 33*16 -> 16B-aligned rows, quad-bank spread

__global__ __launch_bounds__(256) void score_tiles_kernel(
    const float* __restrict__ A,      // [256][128] queries
    const float* __restrict__ bank,   // [n][128]
    int n, int NT,
    float* __restrict__ tilemax) {    // [256][NT]
  const int tile = blockIdx.x;
  const int t = threadIdx.x;
  __shared__ __align__(16) float smem[TILE * LDS_STRIDE];

  // ---- stage tile (64 rows x 128 f32) into LDS, coalesced float4 ----
  const int base = tile * TILE;
#pragma unroll
  for (int j = 0; j < 8; ++j) {
    int idx = t + j * 256;            // 0..2047 float4 slots (64 rows * 32)
    int row = idx >> 5;
    int c4  = idx & 31;
    int g = base + row;
    float4 v = make_float4(0.f, 0.f, 0.f, 0.f);
    if (g < n) v = *(const float4*)(bank + (size_t)g * 128 + c4 * 4);
    *(float4*)(smem + row * LDS_STRIDE + c4 * 4) = v;
  }
  __syncthreads();

  const int wave = t >> 6;
  const int lane = t & 63;
  const int cand = base + lane;
  const bool valid = cand < n;
  const float* srow = smem + lane * LDS_STRIDE;

  // each wave owns 64 queries; process in register-blocked groups of QB=8
  for (int qg = 0; qg < 64; qg += QB) {
    const int q0 = wave * 64 + qg;
    float acc[QB];
#pragma unroll
    for (int j = 0; j < QB; ++j) acc[j] = 0.f;

#pragma unroll 4
    for (int i = 0; i < 128; i += 4) {
      float4 b = *(const float4*)(srow + i);   // per-lane candidate fragment
#pragma unroll
      for (int j = 0; j < QB; ++j) {
        // wave-uniform address -> scalar loads, L1-resident
        float4 a = *(const float4*)(A + (size_t)(q0 + j) * 128 + i);
        acc[j] += a.x * b.x + a.y * b.y + a.z * b.z + a.w * b.w;
      }
    }
#pragma unroll
    for (int j = 0; j < QB; ++j) {
      float v = valid ? acc[j] : -FLT_MAX;
#pragma unroll
      for (int m = 32; m >= 1; m >>= 1)
        v = fmaxf(v, __shfl_xor(v, m, 64));
      if (lane == 0) tilemax[(size_t)(q0 + j) * NT + tile] = v;
    }
  }
}

__global__ __launch_bounds__(256) void finalize_kernel(
    const float* __restrict__ A,      // [256][128]
    const float* __restrict__ bank,   // [n][128]
    int n, int NT,
    const float* __restrict__ tilemax,// [256][NT]
    int* __restrict__ out) {          // [256][KSEL]
  const int q = blockIdx.x;
  const int t = threadIdx.x;

  __shared__ float tv[NT_MAX];
  __shared__ int sel[KSEL];
  __shared__ float rv[256];
  __shared__ int ri[256];
  __shared__ int rs[256];
  __shared__ __align__(16) float aq[128];
  __shared__ float sc[KSEL * TILE];  // 2048 rescored values

  for (int i = t; i < NT; i += 256) tv[i] = tilemax[(size_t)q * NT + i];
  if (t < 128) aq[t] = A[(size_t)q * 128 + t];
  __syncthreads();

  // ---- phase 1: pick the KSEL tiles with largest max ----
  for (int r = 0; r < KSEL; ++r) {
    float bv = -FLT_MAX; int bi = 0x7fffffff;
    for (int i = t; i < NT; i += 256) {
      float v = tv[i];
      if (v > bv || (v == bv && i < bi)) { bv = v; bi = i; }
    }
    rv[t] = bv; ri[t] = bi;
    __syncthreads();
    for (int s = 128; s > 0; s >>= 1) {
      if (t < s) {
        float v2 = rv[t + s]; int i2 = ri[t + s];
        if (v2 > rv[t] || (v2 == rv[t] && i2 < ri[t])) { rv[t] = v2; ri[t] = i2; }
      }
      __syncthreads();
    }
    if (t == 0) { sel[r] = ri[0]; tv[ri[0]] = -FLT_MAX; }
    __syncthreads();
  }

  // ---- phase 2: exact fp32 rescore of the 2048 surviving candidates ----
  for (int j = t; j < KSEL * TILE; j += 256) {
    int tile = sel[j >> 6];
    int cand = tile * TILE + (j & 63);
    float s = -FLT_MAX;
    if (cand < n) {
      const float* row = bank + (size_t)cand * 128;
      float acc = 0.f;
#pragma unroll
      for (int i = 0; i < 128; i += 4) {
        float4 b = *(const float4*)(row + i);
        float4 a = *(const float4*)(aq + i);
        acc += a.x * b.x + a.y * b.y + a.z * b.z + a.w * b.w;
      }
      s = acc;
    }
    sc[j] = s;
  }
  __syncthreads();

  // ---- phase 3: top-KSEL of 2048, value desc / candidate-index asc ----
  for (int r = 0; r < KSEL; ++r) {
    float bv = -FLT_MAX; int bc = 0x7fffffff; int bs = 0;
    for (int j = t; j < KSEL * TILE; j += 256) {
      float v = sc[j];
      int cand = sel[j >> 6] * TILE + (j & 63);
      if (v > bv || (v == bv && cand < bc)) { bv = v; bc = cand; bs = j; }
    }
    rv[t] = bv; ri[t] = bc; rs[t] = bs;
    __syncthreads();
    for (int s = 128; s > 0; s >>= 1) {
      if (t < s) {
        float v2 = rv[t + s]; int c2 = ri[t + s]; int s2 = rs[t + s];
        if (v2 > rv[t] || (v2 == rv[t] && c2 < ri[t])) {
          rv[t] = v2; ri[t] = c2; rs[t] = s2;
        }
      }
      __syncthreads();
    }
    if (t == 0) { out[(size_t)q * KSEL + r] = ri[0]; sc[rs[0]] = -FLT_MAX; }
    __syncthreads();
  }
}

__global__ void mean_gather_kernel(
    const float* __restrict__ bank,   // enc_ctx [n][128]
    const int* __restrict__ ixs,      // [256][KSEL]
    float* __restrict__ outA) {       // [256][128]
  const int q = blockIdx.x;
  const int d = threadIdx.x;          // 128 threads
  float s = 0.f;
  for (int j = 0; j < KSEL; ++j) {
    s += bank[(size_t)ixs[q * KSEL + j] * 128 + d];
  }
  outA[(size_t)q * 128 + d] = s * (1.0f / 32.0f);
}

extern "C" void kernel_launch(void* const* d_in, const int* in_sizes, int n_in,
                              void* d_out, int out_size, void* d_ws, size_t ws_size,
                              hipStream_t stream) {
  const float* contexts = (const float*)d_in[0];  // [256][128]
  const float* enc_ans  = (const float*)d_in[1];  // [n_ans][128]
  const float* enc_ctx  = (const float*)d_in[2];  // [n_ctx][128]
  const int n_ans = in_sizes[1] / 128;
  const int n_ctx = in_sizes[2] / 128;
  const int NT_ctx = (n_ctx + TILE - 1) / TILE;
  const int NT_ans = (n_ans + TILE - 1) / TILE;
  const int NT_big = NT_ctx > NT_ans ? NT_ctx : NT_ans;

  // workspace layout (~8.2 MB): tilemax | c_ixs | new_ctx
  char* ws = (char*)d_ws;
  size_t off = 0;
  float* tilemax = (float*)(ws + off);
  off += ((size_t)256 * NT_big * 4 + 255) & ~(size_t)255;
  int* c_ixs = (int*)(ws + off);
  off += ((size_t)256 * KSEL * 4 + 255) & ~(size_t)255;
  float* new_ctx = (float*)(ws + off);

  // ---- hop 1: contexts vs enc_ctx ----
  score_tiles_kernel<<<NT_ctx, 256, 0, stream>>>(contexts, enc_ctx, n_ctx, NT_ctx, tilemax);
  finalize_kernel<<<256, 256, 0, stream>>>(contexts, enc_ctx, n_ctx, NT_ctx, tilemax, c_ixs);
  mean_gather_kernel<<<256, 128, 0, stream>>>(enc_ctx, c_ixs, new_ctx);

  // ---- hop 2: new_ctx vs enc_ans ----
  score_tiles_kernel<<<NT_ans, 256, 0, stream>>>(new_ctx, enc_ans, n_ans, NT_ans, tilemax);
  finalize_kernel<<<256, 256, 0, stream>>>(new_ctx, enc_ans, n_ans, NT_ans, tilemax, (int*)d_out);
}

// Round 2
// 1400.238 us; speedup vs baseline: 3.2500x; 3.2500x over previous
//
#include <hip/hip_runtime.h>
#include <hip/hip_bf16.h>
#include <float.h>

// OneHopRanker on MI355X — round 2: bf16-MFMA tile-max scoring + exact fp32
// rescore of top-64 tiles per query.
//
// Inputs: d_in[0]=contexts [256x128] f32, d_in[1]=enc_ans [500000x128] f32,
//         d_in[2]=enc_ctx [500000x128] f32, d_in[3]=k (=32).
// Output: d_out = int32 [256x32] answer indices.

#define TILE 64        // candidates per max-tile
#define KSEL 32        // final top-k
#define TSEL 64        // tiles selected per query for exact rescore (safety margin)
#define CB   128       // candidates per score block (2 tiles)
#define LROW 136       // LDS row stride in bf16 elems (272 B: 16B-aligned, conflict-light)
#define NT_MAX 7936    // >= ceil(500000/64)=7813

typedef __attribute__((ext_vector_type(8))) short s16x8;   // 8 bf16 (4 VGPRs)
typedef __attribute__((ext_vector_type(4))) float f32x4;

// ---------------- fp32 -> bf16 (truncation) query conversion ----------------
__global__ void cvt_a_kernel(const float* __restrict__ A,
                             unsigned short* __restrict__ Abf, int nelem) {
  int i = blockIdx.x * 256 + threadIdx.x;
  if (i < nelem) Abf[i] = (unsigned short)(__float_as_uint(A[i]) >> 16);
}

// ---------------- stage 1: fused bf16 GEMM + per-tile max ----------------
// Block: 256 threads = 4 waves. Covers ALL 256 queries x 128 candidates.
// Wave w handles queries [w*64, w*64+64) as 4 q-blocks of 16.
__global__ __launch_bounds__(256) void score_mfma_kernel(
    const unsigned short* __restrict__ Abf,  // [256][128] bf16
    const float* __restrict__ bank,          // [n][128] f32
    int n, int NT,
    float* __restrict__ tilemax) {           // [256][NT]
  __shared__ unsigned short bsm[CB * LROW];  // ~34 KB
  const int t = threadIdx.x;
  const int base = blockIdx.x * CB;

  // ---- stage 128 rows x 128 dims: fp32 global -> bf16 LDS ----
#pragma unroll
  for (int i = 0; i < 16; ++i) {
    int c = t + i * 256;              // 0..4095 float4 chunks
    int row = c >> 5;
    int c4  = c & 31;
    int g = base + row;
    float4 v = make_float4(0.f, 0.f, 0.f, 0.f);
    if (g < n) v = *(const float4*)(bank + (size_t)g * 128 + c4 * 4);
    unsigned int p0 = (__float_as_uint(v.y) & 0xffff0000u) | (__float_as_uint(v.x) >> 16);
    unsigned int p1 = (__float_as_uint(v.w) & 0xffff0000u) | (__float_as_uint(v.z) >> 16);
    *(uint2*)(bsm + row * LROW + c4 * 4) = make_uint2(p0, p1);
  }
  __syncthreads();

  const int wave = t >> 6;
  const int lane = t & 63;
  const int quad = lane >> 4;       // 0..3
  const int lh   = lane & 15;       // 0..15
  const int q0   = wave * 64;

  // ---- cache A fragments in registers: 4 q-blocks x 4 k-steps ----
  // A-frag layout (16x16x32): lane holds A[m=lane&15][k=quad*8 + j]
  s16x8 afr[4][4];
#pragma unroll
  for (int qb = 0; qb < 4; ++qb)
#pragma unroll
    for (int k = 0; k < 4; ++k)
      afr[qb][k] = *(const s16x8*)(Abf + (size_t)(q0 + qb * 16 + lh) * 128 + k * 32 + quad * 8);

#pragma unroll
  for (int tl = 0; tl < 2; ++tl) {
    int tile_g = blockIdx.x * 2 + tl;
    f32x4 vmax[4];
#pragma unroll
    for (int qb = 0; qb < 4; ++qb) vmax[qb] = f32x4{-FLT_MAX, -FLT_MAX, -FLT_MAX, -FLT_MAX};

#pragma unroll
    for (int cb = 0; cb < 4; ++cb) {
      int crow = tl * 64 + cb * 16 + lh;     // candidate row in LDS this lane serves as B col
      s16x8 bfr[4];
#pragma unroll
      for (int k = 0; k < 4; ++k)
        bfr[k] = *(const s16x8*)(bsm + crow * LROW + k * 32 + quad * 8);
#pragma unroll
      for (int qb = 0; qb < 4; ++qb) {
        f32x4 acc = {0.f, 0.f, 0.f, 0.f};
#pragma unroll
        for (int k = 0; k < 4; ++k)
          acc = __builtin_amdgcn_mfma_f32_16x16x32_bf16(afr[qb][k], bfr[k], acc, 0, 0, 0);
#pragma unroll
        for (int r = 0; r < 4; ++r) vmax[qb][r] = fmaxf(vmax[qb][r], acc[r]);
      }
    }

    // reduce max across the 16 candidate columns (lanes lh=0..15 within quad)
    if (tile_g < NT) {
#pragma unroll
      for (int qb = 0; qb < 4; ++qb) {
#pragma unroll
        for (int r = 0; r < 4; ++r) {
          float v = vmax[qb][r];
          v = fmaxf(v, __shfl_xor(v, 1, 64));
          v = fmaxf(v, __shfl_xor(v, 2, 64));
          v = fmaxf(v, __shfl_xor(v, 4, 64));
          v = fmaxf(v, __shfl_xor(v, 8, 64));
          if (lh == 0)
            tilemax[(size_t)(q0 + qb * 16 + quad * 4 + r) * NT + tile_g] = v;
        }
      }
    }
  }
}

// ---------------- stage 2: per-query tile top-T + exact fp32 rescore ----------------
__global__ __launch_bounds__(256) void finalize_kernel(
    const float* __restrict__ A,       // [256][128] fp32 queries (exact)
    const float* __restrict__ bank,    // [n][128]
    int n, int NT,
    const float* __restrict__ tilemax, // [256][NT]
    int* __restrict__ out) {           // [256][KSEL]
  const int q = blockIdx.x;
  const int t = threadIdx.x;
  const int lane = t & 63;
  const int wv = t >> 6;

  __shared__ float tv[NT_MAX];
  __shared__ int sel[TSEL];
  __shared__ __align__(16) float aq[128];
  __shared__ float sc[TSEL * TILE];    // 4096 rescored values
  __shared__ float wrv[4];
  __shared__ int wri[4], wrs[4];

  for (int i = t; i < NT; i += 256) tv[i] = tilemax[(size_t)q * NT + i];
  if (t < 128) aq[t] = A[(size_t)q * 128 + t];
  __syncthreads();

  // ---- phase 1: top-TSEL tiles by (approx) max, iterative argmax ----
  for (int r = 0; r < TSEL; ++r) {
    float bv = -FLT_MAX; int bi = 0x7fffffff;
    for (int i = t; i < NT; i += 256) {
      float v = tv[i];
      if (v > bv || (v == bv && i < bi)) { bv = v; bi = i; }
    }
#pragma unroll
    for (int m = 1; m < 64; m <<= 1) {
      float ov = __shfl_xor(bv, m, 64);
      int   oi = __shfl_xor(bi, m, 64);
      if (ov > bv || (ov == bv && oi < bi)) { bv = ov; bi = oi; }
    }
    if (lane == 0) { wrv[wv] = bv; wri[wv] = bi; }
    __syncthreads();
    if (t == 0) {
      float fv = wrv[0]; int fi = wri[0];
      for (int w = 1; w < 4; ++w)
        if (wrv[w] > fv || (wrv[w] == fv && wri[w] < fi)) { fv = wrv[w]; fi = wri[w]; }
      sel[r] = fi; tv[fi] = -FLT_MAX;
    }
    __syncthreads();
  }

  // ---- phase 2: exact fp32 rescore of 4096 candidates ----
  for (int j = t; j < TSEL * TILE; j += 256) {
    int tile = sel[j >> 6];
    int cand = tile * TILE + (j & 63);
    float s = -FLT_MAX;
    if (cand < n) {
      const float* row = bank + (size_t)cand * 128;
      float a0 = 0.f, a1 = 0.f;
#pragma unroll
      for (int i = 0; i < 128; i += 8) {
        float4 b0 = *(const float4*)(row + i);
        float4 b1 = *(const float4*)(row + i + 4);
        float4 x0 = *(const float4*)(aq + i);
        float4 x1 = *(const float4*)(aq + i + 4);
        a0 += x0.x * b0.x + x0.y * b0.y + x0.z * b0.z + x0.w * b0.w;
        a1 += x1.x * b1.x + x1.y * b1.y + x1.z * b1.z + x1.w * b1.w;
      }
      s = a0 + a1;
    }
    sc[j] = s;
  }
  __syncthreads();

  // ---- phase 3: exact top-KSEL of 4096 (value desc, cand index asc) ----
  for (int r = 0; r < KSEL; ++r) {
    float bv = -FLT_MAX; int bc = 0x7fffffff; int bs = 0;
    for (int j = t; j < TSEL * TILE; j += 256) {
      float v = sc[j];
      int cand = sel[j >> 6] * TILE + (j & 63);
      if (v > bv || (v == bv && cand < bc)) { bv = v; bc = cand; bs = j; }
    }
#pragma unroll
    for (int m = 1; m < 64; m <<= 1) {
      float ov = __shfl_xor(bv, m, 64);
      int   oc = __shfl_xor(bc, m, 64);
      int   os = __shfl_xor(bs, m, 64);
      if (ov > bv || (ov == bv && oc < bc)) { bv = ov; bc = oc; bs = os; }
    }
    if (lane == 0) { wrv[wv] = bv; wri[wv] = bc; wrs[wv] = bs; }
    __syncthreads();
    if (t == 0) {
      float fv = wrv[0]; int fc = wri[0]; int fs = wrs[0];
      for (int w = 1; w < 4; ++w)
        if (wrv[w] > fv || (wrv[w] == fv && wri[w] < fc)) { fv = wrv[w]; fc = wri[w]; fs = wrs[w]; }
      out[(size_t)q * KSEL + r] = fc;
      sc[fs] = -FLT_MAX;
    }
    __syncthreads();
  }
}

// ---------------- gather + mean (fp32 exact) + bf16 copy for hop-2 queries ----------------
__global__ void mean_gather_kernel(
    const float* __restrict__ bank,    // enc_ctx
    const int* __restrict__ ixs,       // [256][KSEL]
    float* __restrict__ outA,          // [256][128] fp32
    unsigned short* __restrict__ outAbf) { // [256][128] bf16
  const int q = blockIdx.x;
  const int d = threadIdx.x;           // 128
  float s = 0.f;
  for (int j = 0; j < KSEL; ++j)
    s += bank[(size_t)ixs[q * KSEL + j] * 128 + d];
  s *= (1.0f / 32.0f);
  outA[(size_t)q * 128 + d] = s;
  outAbf[(size_t)q * 128 + d] = (unsigned short)(__float_as_uint(s) >> 16);
}

extern "C" void kernel_launch(void* const* d_in, const int* in_sizes, int n_in,
                              void* d_out, int out_size, void* d_ws, size_t ws_size,
                              hipStream_t stream) {
  const float* contexts = (const float*)d_in[0];
  const float* enc_ans  = (const float*)d_in[1];
  const float* enc_ctx  = (const float*)d_in[2];
  const int n_ans = in_sizes[1] / 128;
  const int n_ctx = in_sizes[2] / 128;
  const int NT_ctx = (n_ctx + TILE - 1) / TILE;
  const int NT_ans = (n_ans + TILE - 1) / TILE;
  const int NT_big = NT_ctx > NT_ans ? NT_ctx : NT_ans;
  const int NB_ctx = (n_ctx + CB - 1) / CB;
  const int NB_ans = (n_ans + CB - 1) / CB;

  // workspace: tilemax | c_ixs | new_ctx f32 | Abf1 | Abf2
  char* ws = (char*)d_ws;
  size_t off = 0;
  float* tilemax = (float*)(ws + off);
  off += ((size_t)256 * NT_big * 4 + 255) & ~(size_t)255;
  int* c_ixs = (int*)(ws + off);
  off += ((size_t)256 * KSEL * 4 + 255) & ~(size_t)255;
  float* new_ctx = (float*)(ws + off);
  off += ((size_t)256 * 128 * 4 + 255) & ~(size_t)255;
  unsigned short* Abf1 = (unsigned short*)(ws + off);
  off += ((size_t)256 * 128 * 2 + 255) & ~(size_t)255;
  unsigned short* Abf2 = (unsigned short*)(ws + off);

  // ---- hop 1 ----
  cvt_a_kernel<<<128, 256, 0, stream>>>(contexts, Abf1, 256 * 128);
  score_mfma_kernel<<<NB_ctx, 256, 0, stream>>>(Abf1, enc_ctx, n_ctx, NT_ctx, tilemax);
  finalize_kernel<<<256, 256, 0, stream>>>(contexts, enc_ctx, n_ctx, NT_ctx, tilemax, c_ixs);
  mean_gather_kernel<<<256, 128, 0, stream>>>(enc_ctx, c_ixs, new_ctx, Abf2);

  // ---- hop 2 ----
  score_mfma_kernel<<<NB_ans, 256, 0, stream>>>(Abf2, enc_ans, n_ans, NT_ans, tilemax);
  finalize_kernel<<<256, 256, 0, stream>>>(new_ctx, enc_ans, n_ans, NT_ans, tilemax, (int*)d_out);
}